// Round 6
// baseline (773.257 us; speedup 1.0000x reference)
//
#include <hip/hip_runtime.h>

// Group_10: replicate-pad 3x3 conv (4,512,32,32)->(4,9728,32,32) + bias,
// then faithful-PS reinterpretation to (4,152,256,256).
//
// Round 6: LDS-traffic diagnosis -> stream B from global (L2/L3) straight
// to VGPRs; A stays in LDS (global_load_lds, XOR-swizzled pack). MFMA shape
// 32x32x16 (4060 vs 3377 FLOP/cy). 2 phases per K-tile (BK=64 = 4 k16),
// 8 waves (2Mx4N), wave tile 128x64 = 4x2 grid of 32x32 MFMAs.
//   ph1: ds_read A k16{0,1} | stage A(t+1) | SCHED0 | load B(t+1) | BAR
//        LGK0 | MFMA k16{0,1} | BAR
//   ph2: ds_read A k16{2,3} | BAR | LGK0 | MFMA k16{2,3} | VMC8 | BAR
// vmcnt(8): outstanding = A-stage(4,oldest)+B(8) -> retires exactly the
// A stages before the next tile reads that LDS slot. B-reg readiness is
// compiler-enforced (it tracks all VMEM including global_load_lds).

#define CIN   512
#define COUT  9728
#define NBAT  4
#define KTOT  4608
#define KSTEPS 72           // K = 72 * 64
#define MB256  16
#define NB256  38
#define TB     16384        // packed tile: 128 rows x 64 bf16 x 2B
#define PANEL  (KSTEPS * TB)

typedef __bf16 bf16x8 __attribute__((ext_vector_type(8)));
typedef float  f32x16 __attribute__((ext_vector_type(16)));

#define BAR()   __builtin_amdgcn_s_barrier()
#define LGK0()  asm volatile("s_waitcnt lgkmcnt(0)" ::: "memory")
#define VMC8()  asm volatile("s_waitcnt vmcnt(8)" ::: "memory")
#define SCHED0() __builtin_amdgcn_sched_barrier(0)
#define PRIO1() __builtin_amdgcn_s_setprio(1)
#define PRIO0() __builtin_amdgcn_s_setprio(0)

// ---------------- fallback: direct conv (correct, slow) ----------------
__global__ __launch_bounds__(256) void conv_ps_direct(
    const float* __restrict__ x, const float* __restrict__ Wt,
    const float* __restrict__ bias, float* __restrict__ out)
{
    int flat = blockIdx.x * 256 + threadIdx.x;
    int w  = flat & 31;
    int h  = (flat >> 5) & 31;
    int t  = flat >> 10;
    int co = t % COUT;
    int b  = t / COUT;

    const float* xb = x + (size_t)b * CIN * 1024;
    const float* Wc = Wt + (size_t)co * CIN * 9;

    int hm = h > 0  ? h - 1 : 0;
    int hp = h < 31 ? h + 1 : 31;
    int wm = w > 0  ? w - 1 : 0;
    int wp = w < 31 ? w + 1 : 31;

    float acc = bias[co];
    #pragma unroll 4
    for (int ci = 0; ci < CIN; ++ci) {
        const float* xc = xb + ci * 1024;
        const float* wf = Wc + ci * 9;
        const float* r0 = xc + hm * 32;
        const float* r1 = xc + h  * 32;
        const float* r2 = xc + hp * 32;
        acc += wf[0] * r0[wm] + wf[1] * r0[w] + wf[2] * r0[wp];
        acc += wf[3] * r1[wm] + wf[4] * r1[w] + wf[5] * r1[wp];
        acc += wf[6] * r2[wm] + wf[7] * r2[w] + wf[8] * r2[wp];
    }
    int cc = co & 63;
    int n  = co >> 6;
    int i  = ((cc >> 1) << 3) | (w & 7);
    int j  = ((cc & 1) << 7) | ((h >> 1) << 3) | ((h & 1) << 2) | (w >> 3);
    out[(((size_t)b * 152 + n) * 256 + i) * 256 + j] = acc;
}

// ------------- pack W: fp32 -> bf16, tiled, LINEAR (no swizzle) -------------
__global__ __launch_bounds__(256) void pack_W(const float* __restrict__ Wt,
                                              __bf16* __restrict__ Wws)
{
    int G = blockIdx.x * 256 + threadIdx.x;   // < 76*72*128*8
    int s    = G & 7;
    int r    = (G >> 3) & 127;
    int rest = G >> 10;                        // nb128*72 + kt
    int kt = rest % KSTEPS;
    int nb = rest / KSTEPS;
    int n  = nb * 128 + r;
    int k0 = kt * 64 + s * 8;                  // linear: slot == logical granule

    const float* src = Wt + (size_t)n * KTOT + k0;
    float4 v0 = *(const float4*)(src);
    float4 v1 = *(const float4*)(src + 4);
    bf16x8 o;
    o[0] = (__bf16)v0.x; o[1] = (__bf16)v0.y; o[2] = (__bf16)v0.z; o[3] = (__bf16)v0.w;
    o[4] = (__bf16)v1.x; o[5] = (__bf16)v1.y; o[6] = (__bf16)v1.z; o[7] = (__bf16)v1.w;
    *(bf16x8*)(Wws + (size_t)G * 8) = o;
}

// ---------------- pack A: im2col bf16, tiled + XOR-swizzled ----------------
__global__ __launch_bounds__(256) void pack_A(const float* __restrict__ x,
                                              __bf16* __restrict__ Aws)
{
    int G = blockIdx.x * 256 + threadIdx.x;   // < 32*72*128*8
    int s    = G & 7;
    int r    = (G >> 3) & 127;
    int rest = G >> 10;                        // mb128*72 + kt
    int kt = rest % KSTEPS;
    int mb = rest / KSTEPS;
    int m  = mb * 128 + r;
    int b  = m >> 10;
    int h  = (m >> 5) & 31;
    int w  = m & 31;
    int g  = s ^ (r & 7);
    int k0 = kt * 64 + g * 8;

    const float* xb = x + (size_t)b * CIN * 1024;
    bf16x8 o;
    #pragma unroll
    for (int e = 0; e < 8; ++e) {
        int k  = k0 + e;
        int ci = k / 9;
        int r9 = k - ci * 9;
        int kh = r9 / 3;
        int kw = r9 - kh * 3;
        int hh = h + kh - 1; hh = hh < 0 ? 0 : (hh > 31 ? 31 : hh);
        int ww = w + kw - 1; ww = ww < 0 ? 0 : (ww > 31 ? 31 : ww);
        o[e] = (__bf16)xb[(ci << 10) + (hh << 5) + ww];
    }
    *(bf16x8*)(Aws + (size_t)G * 8) = o;
}

// -------- 256x256 GEMM: A via LDS, B via global->reg, 32x32x16 MFMA --------
__global__ __launch_bounds__(512, 2) void gemm_ps(
    const __bf16* __restrict__ Aws, const __bf16* __restrict__ Wws,
    const float* __restrict__ bias, float* __restrict__ out)
{
    // LDS: slot d at d*32768; A halves (128 rows each) at +0 / +16384
    __shared__ __align__(16) char smem[65536];

    // XCD-bijective swizzle: 608 blocks = 8 * 76
    int bid = blockIdx.x;
    int g   = (bid & 7) * 76 + (bid >> 3);
    int mb  = g & 15;
    int nb  = g >> 4;

    int t    = threadIdx.x;
    int lane = t & 63;
    int wid  = t >> 6;
    int wm = wid >> 2, wn = wid & 3;      // 2x4 waves; wave tile 128x64

    const char* Apan0 = (const char*)Aws + (size_t)(mb * 2 + 0) * PANEL;
    const char* Apan1 = (const char*)Aws + (size_t)(mb * 2 + 1) * PANEL;
    int t16 = t * 16;

    auto stageA = [&](const char* a0, const char* a1, int slotBase) {
        __builtin_amdgcn_global_load_lds(
            (const __attribute__((address_space(1))) void*)(a0 + t16),
            (__attribute__((address_space(3))) void*)(smem + slotBase + t16), 16, 0, 0);
        __builtin_amdgcn_global_load_lds(
            (const __attribute__((address_space(1))) void*)(a0 + 8192 + t16),
            (__attribute__((address_space(3))) void*)(smem + slotBase + 8192 + t16), 16, 0, 0);
        __builtin_amdgcn_global_load_lds(
            (const __attribute__((address_space(1))) void*)(a1 + t16),
            (__attribute__((address_space(3))) void*)(smem + slotBase + 16384 + t16), 16, 0, 0);
        __builtin_amdgcn_global_load_lds(
            (const __attribute__((address_space(1))) void*)(a1 + 8192 + t16),
            (__attribute__((address_space(3))) void*)(smem + slotBase + 16384 + 8192 + t16), 16, 0, 0);
    };

    // A ds_read addressing (32x32x16 frag: row=lane&31, kgroup=lane>>5)
    int arow = wm * 16384 + (lane & 31) * 128;
    int ax0 = (((0 * 2) + (lane >> 5)) ^ (lane & 7)) << 4;
    int ax1 = (((1 * 2) + (lane >> 5)) ^ (lane & 7)) << 4;
    int ax2 = (((2 * 2) + (lane >> 5)) ^ (lane & 7)) << 4;
    int ax3 = (((3 * 2) + (lane >> 5)) ^ (lane & 7)) << 4;

    // B global pointers (per ni): col = wn*64 + ni*32 + (lane&31)
    const char* bp0;
    const char* bp1;
    {
        int c0 = wn * 64 + 0 * 32 + (lane & 31);
        int c1 = wn * 64 + 1 * 32 + (lane & 31);
        bp0 = (const char*)Wws + (size_t)(nb * 2 + (c0 >> 7)) * PANEL
              + (c0 & 127) * 128 + ((lane >> 5) << 4);
        bp1 = (const char*)Wws + (size_t)(nb * 2 + (c1 >> 7)) * PANEL
              + (c1 & 127) * 128 + ((lane >> 5) << 4);
    }

    f32x16 acc[4][2] = {};
    bf16x8 b0[8], b1[8];   // [ni*4 + k16]
    bf16x8 af[4][2];

    #define RD(off) (*(const bf16x8*)(smem + (off)))
    #define BLOAD(DST, KT)                                                    \
        { size_t _o = (size_t)(KT) * TB;                                      \
          DST[0] = *(const bf16x8*)(bp0 + _o +  0); \
          DST[1] = *(const bf16x8*)(bp0 + _o + 32); \
          DST[2] = *(const bf16x8*)(bp0 + _o + 64); \
          DST[3] = *(const bf16x8*)(bp0 + _o + 96); \
          DST[4] = *(const bf16x8*)(bp1 + _o +  0); \
          DST[5] = *(const bf16x8*)(bp1 + _o + 32); \
          DST[6] = *(const bf16x8*)(bp1 + _o + 64); \
          DST[7] = *(const bf16x8*)(bp1 + _o + 96); }

    // prologue: A(0) -> slot0 (oldest VMEM), then B(0) regs
    stageA(Apan0, Apan1, 0);
    SCHED0();
    BLOAD(b0, 0);
    VMC8();                 // retires the 4 A stages (oldest of 12)
    BAR();

    #define TILE(T, BC, BN)                                                   \
    {                                                                         \
        const int sb  = ((T) & 1) << 15;                                      \
        const int so  = sb ^ 32768;                                           \
        const int k1  = ((T) + 1 < KSTEPS) ? (T) + 1 : KSTEPS - 1;            \
        /* ---- phase 1: k16 {0,1} ---- */                                    \
        _Pragma("unroll")                                                     \
        for (int mi = 0; mi < 4; ++mi) {                                      \
            af[mi][0] = RD(sb + arow + mi * 4096 + ax0);                      \
            af[mi][1] = RD(sb + arow + mi * 4096 + ax1);                      \
        }                                                                     \
        stageA(Apan0 + (size_t)k1 * TB, Apan1 + (size_t)k1 * TB, so);         \
        SCHED0();                                                             \
        BLOAD(BN, k1);                                                        \
        BAR(); LGK0(); SCHED0();                                              \
        PRIO1();                                                              \
        _Pragma("unroll")                                                     \
        for (int mi = 0; mi < 4; ++mi)                                        \
            _Pragma("unroll")                                                 \
            for (int ni = 0; ni < 2; ++ni) {                                  \
                acc[mi][ni] = __builtin_amdgcn_mfma_f32_32x32x16_bf16(        \
                    af[mi][0], BC[ni * 4 + 0], acc[mi][ni], 0, 0, 0);         \
                acc[mi][ni] = __builtin_amdgcn_mfma_f32_32x32x16_bf16(        \
                    af[mi][1], BC[ni * 4 + 1], acc[mi][ni], 0, 0, 0);         \
            }                                                                 \
        PRIO0();                                                              \
        BAR();                                                                \
        /* ---- phase 2: k16 {2,3} ---- */                                    \
        _Pragma("unroll")                                                     \
        for (int mi = 0; mi < 4; ++mi) {                                      \
            af[mi][0] = RD(sb + arow + mi * 4096 + ax2);                      \
            af[mi][1] = RD(sb + arow + mi * 4096 + ax3);                      \
        }                                                                     \
        BAR(); LGK0(); SCHED0();                                              \
        PRIO1();                                                              \
        _Pragma("unroll")                                                     \
        for (int mi = 0; mi < 4; ++mi)                                        \
            _Pragma("unroll")                                                 \
            for (int ni = 0; ni < 2; ++ni) {                                  \
                acc[mi][ni] = __builtin_amdgcn_mfma_f32_32x32x16_bf16(        \
                    af[mi][0], BC[ni * 4 + 2], acc[mi][ni], 0, 0, 0);         \
                acc[mi][ni] = __builtin_amdgcn_mfma_f32_32x32x16_bf16(        \
                    af[mi][1], BC[ni * 4 + 3], acc[mi][ni], 0, 0, 0);         \
            }                                                                 \
        PRIO0();                                                              \
        VMC8();                                                               \
        BAR();                                                                \
    }

    for (int kt = 0; kt < KSTEPS; kt += 2) {
        TILE(kt,     b0, b1);
        TILE(kt + 1, b1, b0);
    }

    // epilogue: bias + phase-shift scatter (32x32 C/D layout:
    // col = lane&31, row = (reg&3) + 8*(reg>>2) + 4*(lane>>5))
    int M0 = mb * 256 + wm * 128;
    int N0 = nb * 256 + wn * 64;
    int rbase = (lane >> 5) * 4;
    int ncol  = lane & 31;

    #pragma unroll
    for (int ni = 0; ni < 2; ++ni) {
        int n  = N0 + ni * 32 + ncol;
        float bv = bias[n];
        int cc  = n & 63;
        int nch = n >> 6;
        int i_hi = (cc >> 1) << 3;
        int j_hi = (cc & 1) << 7;
        #pragma unroll
        for (int mi = 0; mi < 4; ++mi) {
            #pragma unroll
            for (int r = 0; r < 16; ++r) {
                int row = (r & 3) + ((r >> 2) << 3) + rbase;
                int m = M0 + mi * 32 + row;
                int b = m >> 10, h = (m >> 5) & 31, w = m & 31;
                int i = i_hi | (w & 7);
                int j = j_hi | ((h >> 1) << 3) | ((h & 1) << 2) | (w >> 3);
                out[((size_t)b * 152 + nch) * 65536 + i * 256 + j] =
                    acc[mi][ni][r] + bv;
            }
        }
    }
}

extern "C" void kernel_launch(void* const* d_in, const int* in_sizes, int n_in,
                              void* d_out, int out_size, void* d_ws, size_t ws_size,
                              hipStream_t stream) {
    const float* x    = (const float*)d_in[0];
    const float* Wt   = (const float*)d_in[1];
    const float* bias = (const float*)d_in[2];
    float* out        = (float*)d_out;

    const size_t needW = (size_t)76 * PANEL;  // 89,653,248
    const size_t needA = (size_t)32 * PANEL;  // 37,748,736

    if (ws_size >= needW + needA) {
        __bf16* Wws = (__bf16*)d_ws;
        __bf16* Aws = (__bf16*)((char*)d_ws + needW);
        pack_W<<<21888, 256, 0, stream>>>(Wt, Wws);
        pack_A<<<9216, 256, 0, stream>>>(x, Aws);
        gemm_ps<<<MB256 * NB256, 512, 0, stream>>>(Aws, Wws, bias, out);
    } else {
        const int total = NBAT * COUT * 1024;
        conv_ps_direct<<<total / 256, 256, 0, stream>>>(x, Wt, bias, out);
    }
}

// Round 7
// 612.787 us; speedup vs baseline: 1.2619x; 1.2619x over previous
//
#include <hip/hip_runtime.h>

// Group_10: replicate-pad 3x3 conv (4,512,32,32)->(4,9728,32,32) + bias,
// then faithful-PS reinterpretation to (4,152,256,256).
//
// Round 7: cut LDS traffic structurally.
//  - A: LDS via global_load_lds, GRANULE-MAJOR layout (k-granule outer, row
//    inner) -> conflict-free ds_read_b128 without any XOR.
//  - B: never touches LDS. pack_W emits fragment-packed order so each wave's
//    B load is one coalesced 1KB dwordx4 burst from L2/L3. B regs ping-pong
//    by K-half (kc): b0 loaded in ph2(t-1), used ph1(t); b1 loaded ph1(t),
//    used ph2(t).
//  - Epilogue: per-wave LDS transpose -> float4 coalesced stores (j-runs of
//    16 derived from the PS bijection), bias fused.
// Per K-tile: ph1 {dsA kc0, stage A0(t+1), load b1} BAR LGK0 MFMA32 BAR
//             ph2 {dsA kc1, stage A1(t+1), load b0(t+1)} BAR LGK0 MFMA32
//                 vmcnt(4) BAR   // retires the 4 A-stages, keeps b0 in flight

#define CIN   512
#define COUT  9728
#define NBAT  4
#define KTOT  4608
#define KSTEPS 72           // K = 72 * 64
#define MB256  16
#define NB256  38
#define TB     16384        // packed tile: 16 KB (128 rows/cols x 64 k x 2B)
#define PANEL  (KSTEPS * TB)

typedef __bf16 bf16x8 __attribute__((ext_vector_type(8)));
typedef float  f32x4  __attribute__((ext_vector_type(4)));

#define BAR()   __builtin_amdgcn_s_barrier()
#define LGK0()  asm volatile("s_waitcnt lgkmcnt(0)" ::: "memory")
#define VMC4()  asm volatile("s_waitcnt vmcnt(4)" ::: "memory")
#define SCHED0() __builtin_amdgcn_sched_barrier(0)
#define PRIO1() __builtin_amdgcn_s_setprio(1)
#define PRIO0() __builtin_amdgcn_s_setprio(0)

// ---------------- fallback: direct conv (correct, slow) ----------------
__global__ __launch_bounds__(256) void conv_ps_direct(
    const float* __restrict__ x, const float* __restrict__ Wt,
    const float* __restrict__ bias, float* __restrict__ out)
{
    int flat = blockIdx.x * 256 + threadIdx.x;
    int w  = flat & 31;
    int h  = (flat >> 5) & 31;
    int t  = flat >> 10;
    int co = t % COUT;
    int b  = t / COUT;

    const float* xb = x + (size_t)b * CIN * 1024;
    const float* Wc = Wt + (size_t)co * CIN * 9;

    int hm = h > 0  ? h - 1 : 0;
    int hp = h < 31 ? h + 1 : 31;
    int wm = w > 0  ? w - 1 : 0;
    int wp = w < 31 ? w + 1 : 31;

    float acc = bias[co];
    #pragma unroll 4
    for (int ci = 0; ci < CIN; ++ci) {
        const float* xc = xb + ci * 1024;
        const float* wf = Wc + ci * 9;
        const float* r0 = xc + hm * 32;
        const float* r1 = xc + h  * 32;
        const float* r2 = xc + hp * 32;
        acc += wf[0] * r0[wm] + wf[1] * r0[w] + wf[2] * r0[wp];
        acc += wf[3] * r1[wm] + wf[4] * r1[w] + wf[5] * r1[wp];
        acc += wf[6] * r2[wm] + wf[7] * r2[w] + wf[8] * r2[wp];
    }
    int cc = co & 63;
    int n  = co >> 6;
    int i  = ((cc >> 1) << 3) | (w & 7);
    int j  = ((cc & 1) << 7) | ((h >> 1) << 3) | ((h & 1) << 2) | (w >> 3);
    out[(((size_t)b * 152 + n) * 256 + i) * 256 + j] = acc;
}

// -------- pack W: fp32 -> bf16, FRAGMENT-PACKED for coalesced B loads ------
// Tile (nbl128, kt) = 16 KB = 16 frags x 1 KB. frag f = cgrp*2 + kc;
// entry l (lane): col = nbl*128 + cgrp*16 + (l&15),
//                 k   = kt*64 + (kc*4 + (l>>4))*8 .. +8
__global__ __launch_bounds__(256) void pack_W(const float* __restrict__ Wt,
                                              __bf16* __restrict__ Wws)
{
    int G = blockIdx.x * 256 + threadIdx.x;   // granules, < 76*72*1024
    int gt   = G & 1023;
    int f    = gt >> 6;
    int l    = gt & 63;
    int rest = G >> 10;                        // nbl*72 + kt
    int kt  = rest % KSTEPS;
    int nbl = rest / KSTEPS;
    int cgrp = f >> 1;
    int kc   = f & 1;
    int n  = nbl * 128 + cgrp * 16 + (l & 15);
    int k0 = kt * 64 + (kc * 4 + (l >> 4)) * 8;

    const float* src = Wt + (size_t)n * KTOT + k0;
    float4 v0 = *(const float4*)(src);
    float4 v1 = *(const float4*)(src + 4);
    bf16x8 o;
    o[0] = (__bf16)v0.x; o[1] = (__bf16)v0.y; o[2] = (__bf16)v0.z; o[3] = (__bf16)v0.w;
    o[4] = (__bf16)v1.x; o[5] = (__bf16)v1.y; o[6] = (__bf16)v1.z; o[7] = (__bf16)v1.w;
    *(bf16x8*)(Wws + (size_t)G * 8) = o;
}

// -------- pack A: im2col bf16, GRANULE-MAJOR (g outer, row inner) ----------
// Tile (mb128, kt): offset = g*2048 + r*16 bytes; g = k-granule, r = row.
__global__ __launch_bounds__(256) void pack_A(const float* __restrict__ x,
                                              __bf16* __restrict__ Aws)
{
    int G = blockIdx.x * 256 + threadIdx.x;   // granules, < 32*72*1024
    int r    = G & 127;
    int g    = (G >> 7) & 7;
    int rest = G >> 10;                        // mb*72 + kt
    int kt = rest % KSTEPS;
    int mb = rest / KSTEPS;
    int m  = mb * 128 + r;
    int b  = m >> 10;
    int h  = (m >> 5) & 31;
    int w  = m & 31;
    int k0 = kt * 64 + g * 8;

    const float* xb = x + (size_t)b * CIN * 1024;
    bf16x8 o;
    #pragma unroll
    for (int e = 0; e < 8; ++e) {
        int k  = k0 + e;
        int ci = k / 9;
        int r9 = k - ci * 9;
        int kh = r9 / 3;
        int kw = r9 - kh * 3;
        int hh = h + kh - 1; hh = hh < 0 ? 0 : (hh > 31 ? 31 : hh);
        int ww = w + kw - 1; ww = ww < 0 ? 0 : (ww > 31 ? 31 : ww);
        o[e] = (__bf16)xb[(ci << 10) + (hh << 5) + ww];
    }
    *(bf16x8*)(Aws + (size_t)G * 8) = o;
}

// ------ 256x256 GEMM: A in LDS (granule-major), B global->reg, fused PS ----
__global__ __launch_bounds__(512, 2) void gemm_ps(
    const __bf16* __restrict__ Aws, const __bf16* __restrict__ Wws,
    const float* __restrict__ bias, float* __restrict__ out)
{
    // K-loop: A dbuf slots at 0/32768 (each 32 KB: half0 +0, half1 +16384).
    // Epilogue: per-wave 16 KB slices over the full 128 KB.
    __shared__ __align__(16) char smem[131072];

    // XCD-bijective swizzle: 608 blocks = 8 * 76
    int bid = blockIdx.x;
    int g   = (bid & 7) * 76 + (bid >> 3);
    int mb  = g & 15;
    int nb  = g >> 4;

    int t    = threadIdx.x;
    int lane = t & 63;
    int wid  = t >> 6;
    int wm = wid >> 2, wn = wid & 3;      // 2x4 waves; wave tile 128x64

    const char* Apan0 = (const char*)Aws + (size_t)(mb * 2 + 0) * PANEL;
    const char* Apan1 = (const char*)Aws + (size_t)(mb * 2 + 1) * PANEL;
    const char* Bpan  = (const char*)Wws + (size_t)(nb * 2 + (wn >> 1)) * PANEL;
    int t16 = t * 16;

    // B frag base pointers: cgrp = (wn&1)*4 + ni, frag stride 2048 (kc pair)
    const char* bp0 = Bpan + ((size_t)((wn & 1) * 4 + 0) * 2048) + lane * 16;
    const char* bp1 = Bpan + ((size_t)((wn & 1) * 4 + 1) * 2048) + lane * 16;
    const char* bp2 = Bpan + ((size_t)((wn & 1) * 4 + 2) * 2048) + lane * 16;
    const char* bp3 = Bpan + ((size_t)((wn & 1) * 4 + 3) * 2048) + lane * 16;

    auto stage2 = [&](const char* src, int ldsOff) {  // one 16 KB half-tile
        __builtin_amdgcn_global_load_lds(
            (const __attribute__((address_space(1))) void*)(src + t16),
            (__attribute__((address_space(3))) void*)(smem + ldsOff + t16), 16, 0, 0);
        __builtin_amdgcn_global_load_lds(
            (const __attribute__((address_space(1))) void*)(src + 8192 + t16),
            (__attribute__((address_space(3))) void*)(smem + ldsOff + 8192 + t16), 16, 0, 0);
    };

    // A ds_read: addr = slot + wm*16384 + g*2048 + (mi*16 + lane&15)*16
    int abase = wm * 16384 + ((lane & 15) << 4);
    int g0 = (lane >> 4) << 11;            // kc0 granule block
    int g1 = (4 + (lane >> 4)) << 11;      // kc1

    f32x4 acc[8][4] = {};
    bf16x8 af[8], b0f[4], b1f[4];

    #define RD(off) (*(const bf16x8*)(smem + (off)))
    #define BLOAD(DST, KT, KC)                                                \
        { size_t _o = (size_t)(KT) * TB + (size_t)(KC) * 1024;                \
          DST[0] = *(const bf16x8*)(bp0 + _o);                                \
          DST[1] = *(const bf16x8*)(bp1 + _o);                                \
          DST[2] = *(const bf16x8*)(bp2 + _o);                                \
          DST[3] = *(const bf16x8*)(bp3 + _o); }

    // prologue: stage A(0) -> slot0; load b0(kt0,kc0)
    stage2(Apan0, 0);
    stage2(Apan1, 16384);
    SCHED0();
    BLOAD(b0f, 0, 0);
    VMC4();                 // retire the 4 A stages; b0 stays in flight
    BAR();

    for (int kt = 0; kt < KSTEPS; ++kt) {
        int sb  = (kt & 1) << 15;
        int so  = sb ^ 32768;
        int kt1 = kt + 1 < KSTEPS ? kt + 1 : KSTEPS - 1;

        // ---- phase 1: kc0 ----
        #pragma unroll
        for (int mi = 0; mi < 8; ++mi)
            af[mi] = RD(sb + abase + g0 + mi * 256);
        stage2(Apan0 + (size_t)kt1 * TB, so);
        SCHED0();
        BLOAD(b1f, kt, 1);
        BAR(); LGK0(); SCHED0();
        PRIO1();
        #pragma unroll
        for (int mi = 0; mi < 8; ++mi)
            #pragma unroll
            for (int ni = 0; ni < 4; ++ni)
                acc[mi][ni] = __builtin_amdgcn_mfma_f32_16x16x32_bf16(
                    af[mi], b0f[ni], acc[mi][ni], 0, 0, 0);
        PRIO0();
        BAR();

        // ---- phase 2: kc1 ----
        #pragma unroll
        for (int mi = 0; mi < 8; ++mi)
            af[mi] = RD(sb + abase + g1 + mi * 256);
        stage2(Apan1 + (size_t)kt1 * TB, so + 16384);
        SCHED0();
        BLOAD(b0f, kt1, 0);
        BAR(); LGK0(); SCHED0();
        PRIO1();
        #pragma unroll
        for (int mi = 0; mi < 8; ++mi)
            #pragma unroll
            for (int ni = 0; ni < 4; ++ni)
                acc[mi][ni] = __builtin_amdgcn_mfma_f32_16x16x32_bf16(
                    af[mi], b1f[ni], acc[mi][ni], 0, 0, 0);
        PRIO0();
        VMC4();   // retire this tile's 4 A-stages; keep b0(kt+1) in flight
        BAR();
    }

    // ---- epilogue: per-wave LDS transpose -> coalesced float4 stores ----
    // Wave covers (b, nch) plane rows il=0..255 fully; chunk mh = 64 m-rows.
    int M0 = mb * 256 + wm * 128;
    int N0 = nb * 256 + wn * 64;
    int nch0 = N0 >> 6;
    float* slice = (float*)(smem + wid * 16384);

    float bv[4];
    #pragma unroll
    for (int ni = 0; ni < 4; ++ni)
        bv[ni] = bias[N0 + ni * 16 + (lane & 15)];

    int cc_lo = lane & 15;     // cc = ni*16 + cc_lo
    int l4    = lane >> 4;

    #pragma unroll
    for (int mh = 0; mh < 2; ++mh) {
        // scatter acc -> slice[il*16 + jl]
        #pragma unroll
        for (int mi4 = 0; mi4 < 4; ++mi4) {
            int mi = mh * 4 + mi4;
            #pragma unroll
            for (int r = 0; r < 4; ++r) {
                int moff = mi * 16 + l4 * 4 + r;    // within 128-row wave tile
                int w  = moff & 31;
                int hb = (moff >> 5) & 1;
                #pragma unroll
                for (int ni = 0; ni < 4; ++ni) {
                    int cc = ni * 16 + cc_lo;
                    int il = ((cc >> 1) << 3) | (w & 7);
                    int jl = ((cc & 1) << 3) | (hb << 2) | (w >> 3);
                    slice[il * 16 + jl] = acc[mi][ni][r] + bv[ni];
                }
            }
        }
        LGK0(); SCHED0();
        // gather float4 runs -> global
        int mm0 = M0 + mh * 64;
        int bb  = mm0 >> 10;
        int h0  = (mm0 >> 5) & 31;          // even
        int jh8 = (h0 >> 1) << 3;
        float* plane = out + ((size_t)bb * 152 + nch0) * 65536;
        #pragma unroll
        for (int iter = 0; iter < 16; ++iter) {
            int idx = iter * 64 + lane;
            int il  = idx >> 2;
            int run = idx & 3;
            f32x4 v = *(const f32x4*)(slice + il * 16 + run * 4);
            int j = ((run >> 1) << 7) + jh8 + ((run & 1) << 2);
            *(f32x4*)(plane + il * 256 + j) = v;
        }
        LGK0(); SCHED0();
    }
}

extern "C" void kernel_launch(void* const* d_in, const int* in_sizes, int n_in,
                              void* d_out, int out_size, void* d_ws, size_t ws_size,
                              hipStream_t stream) {
    const float* x    = (const float*)d_in[0];
    const float* Wt   = (const float*)d_in[1];
    const float* bias = (const float*)d_in[2];
    float* out        = (float*)d_out;

    const size_t needW = (size_t)76 * PANEL;  // 89,653,248
    const size_t needA = (size_t)32 * PANEL;  // 37,748,736

    if (ws_size >= needW + needA) {
        __bf16* Wws = (__bf16*)d_ws;
        __bf16* Aws = (__bf16*)((char*)d_ws + needW);
        pack_W<<<21888, 256, 0, stream>>>(Wt, Wws);
        pack_A<<<9216, 256, 0, stream>>>(x, Aws);
        gemm_ps<<<MB256 * NB256, 512, 0, stream>>>(Aws, Wws, bias, out);
    } else {
        const int total = NBAT * COUT * 1024;
        conv_ps_direct<<<total / 256, 256, 0, stream>>>(x, Wt, bias, out);
    }
}

// Round 8
// 548.983 us; speedup vs baseline: 1.4085x; 1.1162x over previous
//
#include <hip/hip_runtime.h>

// Group_10: replicate-pad 3x3 conv (4,512,32,32)->(4,9728,32,32) + bias,
// then faithful-PS reinterpretation to (4,152,256,256).
//
// Round 8: proven pieces, overlap regime.
//  - 128x128 tile, 4 waves (2x2, wave 64x64), 2 phases/K-tile (R3 core).
//  - A: LDS 2x16KB dbuf via global_load_lds, granule-major pack (R7) -> 0
//    conflicts, no XOR. B: frag-packed global->VGPR (R7 pack, verified),
//    1 coalesced 1KB burst per frag from L2; never touches LDS.
//  - LDS 32 KB + launch_bounds(256,3) -> 3 blocks/CU co-resident: stall
//    windows of one block covered by the others (m97 overlap mechanism).
//  - Epilogue: R3's direct scatter (verified WRITE ~175MB, no LDS).

#define CIN   512
#define COUT  9728
#define NBAT  4
#define KTOT  4608
#define KSTEPS 72           // K = 72 * 64
#define TB     16384        // packed tile: 16 KB
#define PANEL  (KSTEPS * TB)

typedef __bf16 bf16x8 __attribute__((ext_vector_type(8)));
typedef float  f32x4  __attribute__((ext_vector_type(4)));

#define BAR()   __builtin_amdgcn_s_barrier()
#define LGK0()  asm volatile("s_waitcnt lgkmcnt(0)" ::: "memory")
#define VMC4()  asm volatile("s_waitcnt vmcnt(4)" ::: "memory")
#define SCHED0() __builtin_amdgcn_sched_barrier(0)
#define PRIO1() __builtin_amdgcn_s_setprio(1)
#define PRIO0() __builtin_amdgcn_s_setprio(0)

// ---------------- fallback: direct conv (correct, slow) ----------------
__global__ __launch_bounds__(256) void conv_ps_direct(
    const float* __restrict__ x, const float* __restrict__ Wt,
    const float* __restrict__ bias, float* __restrict__ out)
{
    int flat = blockIdx.x * 256 + threadIdx.x;
    int w  = flat & 31;
    int h  = (flat >> 5) & 31;
    int t  = flat >> 10;
    int co = t % COUT;
    int b  = t / COUT;

    const float* xb = x + (size_t)b * CIN * 1024;
    const float* Wc = Wt + (size_t)co * CIN * 9;

    int hm = h > 0  ? h - 1 : 0;
    int hp = h < 31 ? h + 1 : 31;
    int wm = w > 0  ? w - 1 : 0;
    int wp = w < 31 ? w + 1 : 31;

    float acc = bias[co];
    #pragma unroll 4
    for (int ci = 0; ci < CIN; ++ci) {
        const float* xc = xb + ci * 1024;
        const float* wf = Wc + ci * 9;
        const float* r0 = xc + hm * 32;
        const float* r1 = xc + h  * 32;
        const float* r2 = xc + hp * 32;
        acc += wf[0] * r0[wm] + wf[1] * r0[w] + wf[2] * r0[wp];
        acc += wf[3] * r1[wm] + wf[4] * r1[w] + wf[5] * r1[wp];
        acc += wf[6] * r2[wm] + wf[7] * r2[w] + wf[8] * r2[wp];
    }
    int cc = co & 63;
    int n  = co >> 6;
    int i  = ((cc >> 1) << 3) | (w & 7);
    int j  = ((cc & 1) << 7) | ((h >> 1) << 3) | ((h & 1) << 2) | (w >> 3);
    out[(((size_t)b * 152 + n) * 256 + i) * 256 + j] = acc;
}

// -------- pack W: fp32 -> bf16, FRAGMENT-PACKED (verified R7) --------
// Tile (nbl128, kt) = 16 KB = 16 frags x 1 KB. frag f = cgrp*2 + kc;
// lane l: col = nbl*128 + cgrp*16 + (l&15), k = kt*64 + (kc*4 + (l>>4))*8..+8
__global__ __launch_bounds__(256) void pack_W(const float* __restrict__ Wt,
                                              __bf16* __restrict__ Wws)
{
    int G = blockIdx.x * 256 + threadIdx.x;   // granules, < 76*72*1024
    int gt   = G & 1023;
    int f    = gt >> 6;
    int l    = gt & 63;
    int rest = G >> 10;                        // nbl*72 + kt
    int kt  = rest % KSTEPS;
    int nbl = rest / KSTEPS;
    int cgrp = f >> 1;
    int kc   = f & 1;
    int n  = nbl * 128 + cgrp * 16 + (l & 15);
    int k0 = kt * 64 + (kc * 4 + (l >> 4)) * 8;

    const float* src = Wt + (size_t)n * KTOT + k0;
    float4 v0 = *(const float4*)(src);
    float4 v1 = *(const float4*)(src + 4);
    bf16x8 o;
    o[0] = (__bf16)v0.x; o[1] = (__bf16)v0.y; o[2] = (__bf16)v0.z; o[3] = (__bf16)v0.w;
    o[4] = (__bf16)v1.x; o[5] = (__bf16)v1.y; o[6] = (__bf16)v1.z; o[7] = (__bf16)v1.w;
    *(bf16x8*)(Wws + (size_t)G * 8) = o;
}

// ----- pack A: im2col bf16, GRANULE-MAJOR (verified R7, 0 conflicts) -----
// Tile (mb128, kt): offset = g*2048 + r*16 bytes; g = k-granule, r = row.
__global__ __launch_bounds__(256) void pack_A(const float* __restrict__ x,
                                              __bf16* __restrict__ Aws)
{
    int G = blockIdx.x * 256 + threadIdx.x;   // granules, < 32*72*1024
    int r    = G & 127;
    int g    = (G >> 7) & 7;
    int rest = G >> 10;                        // mb*72 + kt
    int kt = rest % KSTEPS;
    int mb = rest / KSTEPS;
    int m  = mb * 128 + r;
    int b  = m >> 10;
    int h  = (m >> 5) & 31;
    int w  = m & 31;
    int k0 = kt * 64 + g * 8;

    const float* xb = x + (size_t)b * CIN * 1024;
    bf16x8 o;
    #pragma unroll
    for (int e = 0; e < 8; ++e) {
        int k  = k0 + e;
        int ci = k / 9;
        int r9 = k - ci * 9;
        int kh = r9 / 3;
        int kw = r9 - kh * 3;
        int hh = h + kh - 1; hh = hh < 0 ? 0 : (hh > 31 ? 31 : hh);
        int ww = w + kw - 1; ww = ww < 0 ? 0 : (ww > 31 ? 31 : ww);
        o[e] = (__bf16)xb[(ci << 10) + (hh << 5) + ww];
    }
    *(bf16x8*)(Aws + (size_t)G * 8) = o;
}

// ---- 128x128 GEMM: A in LDS (granule-major), B global->reg, fused PS ----
__global__ __launch_bounds__(256, 3) void gemm_ps(
    const __bf16* __restrict__ Aws, const __bf16* __restrict__ Wws,
    const float* __restrict__ bias, float* __restrict__ out)
{
    __shared__ __align__(16) char smem[32768];   // 2 x 16 KB A dbuf

    // XCD-bijective swizzle: 2432 blocks = 8 * 304; 32 consecutive g share nb
    int bid = blockIdx.x;
    int g   = (bid & 7) * 304 + (bid >> 3);
    int mb  = g & 31;
    int nb  = g >> 5;

    int t    = threadIdx.x;
    int lane = t & 63;
    int wid  = t >> 6;
    int wm = wid >> 1, wn = wid & 1;      // 2x2 waves; wave tile 64x64

    const char* Apan = (const char*)Aws + (size_t)mb * PANEL;
    const char* Bpan = (const char*)Wws + (size_t)nb * PANEL;
    int t16 = t * 16;

    auto stage = [&](const char* src, int ldsOff) {  // one 4 KB chunk
        __builtin_amdgcn_global_load_lds(
            (const __attribute__((address_space(1))) void*)(src + t16),
            (__attribute__((address_space(3))) void*)(smem + ldsOff + t16), 16, 0, 0);
    };

    // B frag base pointers: cgrp = wn*4 + ni
    const char* bp0 = Bpan + ((size_t)(wn * 4 + 0) * 2048) + lane * 16;
    const char* bp1 = Bpan + ((size_t)(wn * 4 + 1) * 2048) + lane * 16;
    const char* bp2 = Bpan + ((size_t)(wn * 4 + 2) * 2048) + lane * 16;
    const char* bp3 = Bpan + ((size_t)(wn * 4 + 3) * 2048) + lane * 16;

    // A ds_read: addr = slot + (kc*4 + lane>>4)*2048 + (wm*64 + mi*16 + lane&15)*16
    int aoff = ((lane >> 4) << 11) + ((wm * 64 + (lane & 15)) << 4);

    f32x4 acc[4][4] = {};
    bf16x8 af[4], b0f[4], b1f[4];

    #define RD(off) (*(const bf16x8*)(smem + (off)))
    #define BLOAD(DST, KT, KC)                                                \
        { size_t _o = (size_t)(KT) * TB + (size_t)(KC) * 1024;                \
          DST[0] = *(const bf16x8*)(bp0 + _o);                                \
          DST[1] = *(const bf16x8*)(bp1 + _o);                                \
          DST[2] = *(const bf16x8*)(bp2 + _o);                                \
          DST[3] = *(const bf16x8*)(bp3 + _o); }

    // prologue: stage A(0) -> slot0 (4 gloads), then b0f(0,kc0)
    stage(Apan + 0,     0);
    stage(Apan + 4096,  4096);
    stage(Apan + 8192,  8192);
    stage(Apan + 12288, 12288);
    SCHED0();
    BLOAD(b0f, 0, 0);
    VMC4();                 // retire the 4 A stages; b0f stays in flight
    BAR();

    for (int kt = 0; kt < KSTEPS; ++kt) {
        int sb  = (kt & 1) << 14;
        int so  = sb ^ 16384;
        int kt1 = kt + 1 < KSTEPS ? kt + 1 : KSTEPS - 1;
        const char* An = Apan + (size_t)kt1 * TB;

        // ---- phase 1: kc0 ----
        #pragma unroll
        for (int mi = 0; mi < 4; ++mi)
            af[mi] = RD(sb + aoff + mi * 256);
        stage(An + 0,    so + 0);
        stage(An + 4096, so + 4096);
        SCHED0();
        BLOAD(b1f, kt, 1);
        BAR(); LGK0(); SCHED0();
        PRIO1();
        #pragma unroll
        for (int mi = 0; mi < 4; ++mi)
            #pragma unroll
            for (int ni = 0; ni < 4; ++ni)
                acc[mi][ni] = __builtin_amdgcn_mfma_f32_16x16x32_bf16(
                    af[mi], b0f[ni], acc[mi][ni], 0, 0, 0);
        PRIO0();
        BAR();

        // ---- phase 2: kc1 ----
        #pragma unroll
        for (int mi = 0; mi < 4; ++mi)
            af[mi] = RD(sb + aoff + 8192 + mi * 256);
        stage(An + 8192,  so + 8192);
        stage(An + 12288, so + 12288);
        SCHED0();
        BLOAD(b0f, kt1, 0);
        BAR(); LGK0(); SCHED0();
        PRIO1();
        #pragma unroll
        for (int mi = 0; mi < 4; ++mi)
            #pragma unroll
            for (int ni = 0; ni < 4; ++ni)
                acc[mi][ni] = __builtin_amdgcn_mfma_f32_16x16x32_bf16(
                    af[mi], b1f[ni], acc[mi][ni], 0, 0, 0);
        PRIO0();
        VMC4();   // retire this tile's 4 A-stages; keep b0f(kt+1) in flight
        BAR();
    }

    // epilogue: bias + phase-shift scatter (verified R3; WRITE ~ideal)
    int M0 = mb * 128 + wm * 64;
    int N0 = nb * 128 + wn * 64;
    int nlane = lane & 15;
    int mrow  = (lane >> 4) * 4;

    #pragma unroll
    for (int ni = 0; ni < 4; ++ni) {
        int n  = N0 + ni * 16 + nlane;
        float bv = bias[n];
        int cc  = n & 63;
        int nch = n >> 6;
        int i_hi = (cc >> 1) << 3;
        int j_hi = (cc & 1) << 7;
        #pragma unroll
        for (int mi = 0; mi < 4; ++mi) {
            #pragma unroll
            for (int r = 0; r < 4; ++r) {
                int m = M0 + mi * 16 + mrow + r;
                int b = m >> 10, h = (m >> 5) & 31, w = m & 31;
                int i = i_hi | (w & 7);
                int j = j_hi | ((h >> 1) << 3) | ((h & 1) << 2) | (w >> 3);
                out[((size_t)b * 152 + nch) * 65536 + i * 256 + j] =
                    acc[mi][ni][r] + bv;
            }
        }
    }
}

extern "C" void kernel_launch(void* const* d_in, const int* in_sizes, int n_in,
                              void* d_out, int out_size, void* d_ws, size_t ws_size,
                              hipStream_t stream) {
    const float* x    = (const float*)d_in[0];
    const float* Wt   = (const float*)d_in[1];
    const float* bias = (const float*)d_in[2];
    float* out        = (float*)d_out;

    const size_t needW = (size_t)76 * PANEL;  // 89,653,248
    const size_t needA = (size_t)32 * PANEL;  // 37,748,736

    if (ws_size >= needW + needA) {
        __bf16* Wws = (__bf16*)d_ws;
        __bf16* Aws = (__bf16*)((char*)d_ws + needW);
        pack_W<<<21888, 256, 0, stream>>>(Wt, Wws);
        pack_A<<<9216, 256, 0, stream>>>(x, Aws);
        gemm_ps<<<32 * 76, 256, 0, stream>>>(Aws, Wws, bias, out);
    } else {
        const int total = NBAT * COUT * 1024;
        conv_ps_direct<<<total / 256, 256, 0, stream>>>(x, Wt, bias, out);
    }
}